// Round 25
// baseline (522.242 us; speedup 1.0000x reference)
//
#include <hip/hip_runtime.h>
#include <hip/hip_bf16.h>
#include <cstdint>
#include <cstddef>

// B=2048, D=256, H=256, N=64, F=513, 4H=1024

typedef short s16x8 __attribute__((ext_vector_type(8)));
typedef float f32x4 __attribute__((ext_vector_type(4)));
typedef int   i32x4 __attribute__((ext_vector_type(4)));
typedef unsigned short u16x4 __attribute__((ext_vector_type(4)));

static __device__ __forceinline__ unsigned short f2b(float f){
  union{float f; unsigned int u;} v; v.f = f;
  unsigned int r = v.u + 0x7fffu + ((v.u >> 16) & 1u);   // RNE
  return (unsigned short)(r >> 16);
}
static __device__ __forceinline__ float b2f(unsigned short h){
  union{unsigned int u; float f;} v; v.u = ((unsigned int)h) << 16; return v.f;
}
static __device__ __forceinline__ unsigned int pack2(float a, float b){
  return (unsigned int)f2b(a) | ((unsigned int)f2b(b) << 16);
}
static __device__ __forceinline__ float fsig(float x){ return 1.0f / (1.0f + __expf(-x)); }
static __device__ __forceinline__ float ftanh(float x){ return 2.0f / (1.0f + __expf(-2.0f * x)) - 1.0f; }
static __device__ __forceinline__ float wred(float p){
  p += __shfl_down(p, 32); p += __shfl_down(p, 16); p += __shfl_down(p, 8);
  p += __shfl_down(p, 4);  p += __shfl_down(p, 2);  p += __shfl_down(p, 1);
  return p;
}
// async global->LDS, 16 B per lane; lds base wave-uniform, global src per-lane
static __device__ __forceinline__ void gload16(const void* g, void* lds){
  __builtin_amdgcn_global_load_lds(
      (const __attribute__((address_space(1))) unsigned int*)g,
      (__attribute__((address_space(3))) unsigned int*)lds, 16, 0, 0);
}

#define WSCALE (0.30f / 127.0f)      // W_hh i8 scale

// ---------------------------------------------------------------------------
// K1+K0 fused: blocks 0..2047 = routing; blocks 2048..4095 = weight prep.
// ---------------------------------------------------------------------------
__global__ __launch_bounds__(256) void k_route(
    const float* __restrict__ x, const float* __restrict__ slots,
    const float* __restrict__ delta, const int* __restrict__ filled,
    const float* __restrict__ Wq, const float* __restrict__ Wk,
    const float* __restrict__ Wv, const float* __restrict__ bv,
    const float* __restrict__ wih, const float* __restrict__ whh,
    const float* __restrict__ bih, const float* __restrict__ bhh,
    int* __restrict__ idx_ws, float* __restrict__ v_ws,
    float* __restrict__ delta_out, float* __restrict__ filled_out,
    unsigned short* __restrict__ wfB, signed char* __restrict__ wfrag8,
    float* __restrict__ bias, float* __restrict__ wlast){
  int tid = threadIdx.x;
  if (blockIdx.x >= 2048){                 // ---- prep branch ----
    int id = (blockIdx.x - 2048) * 256 + tid;   // covers 524288
    { // wfB: 1024 frags * 512 entries, kt-major
      int frag = id >> 9;
      int l = (id >> 3) & 63;
      int j = id & 7;
      int kt = frag >> 6, ct = frag & 63;
      int col = ct * 16 + (l & 15);
      int k   = kt * 32 + (l >> 4) * 8 + j;
      wfB[id] = f2b(wih[col * 513 + k]);
    }
    if (id < 262144){ // wfrag8: 256 frags * 64 lanes * 16 B (K=64 layout)
      int frag = id >> 10;
      int lane = (id >> 4) & 63;
      int j    = id & 15;
      int w   = frag >> 5;
      int kt2 = (frag >> 3) & 3;
      int nt  = frag & 7;
      int g   = nt >> 1, hh = nt & 1;
      int colg = g * 256 + w * 32 + hh * 16 + (lane & 15);
      int k    = kt2 * 64 + (lane >> 4) * 16 + j;
      int q = __float2int_rn(whh[colg * 256 + k] * (1.0f / WSCALE));
      q = q > 127 ? 127 : (q < -127 ? -127 : q);
      wfrag8[id] = (signed char)q;
    }
    if (id < 1024){
      bias[id]  = bih[id] + bhh[id];
      wlast[id] = wih[id * 513 + 512];
    }
    return;
  }
  // ---- routing branch ----
  int b = blockIdx.x, l = tid & 63, w = tid >> 6;
  __shared__ float xs[256], qs[256], qks[256], sims[64];
  __shared__ int sidx;
  xs[tid] = x[b * 256 + tid];
  if (tid < 64){
    unsigned long long em = __ballot(filled[b * 64 + tid] == 0);
    if (tid == 0) sidx = em ? (int)__builtin_ctzll(em) : -1;
  }
  __syncthreads();
  for (int t = 0; t < 64; ++t){
    int h = w * 64 + t;
    float pv = 0.f;
    #pragma unroll
    for (int j2 = 0; j2 < 4; ++j2)
      pv += Wv[h * 256 + l + 64 * j2] * xs[l + 64 * j2];
    pv = wred(pv);
    if (l == 0) v_ws[b * 256 + h] = pv + bv[h];
  }
  if (sidx < 0){           // rare fallback: content-based argmax
    for (int t = 0; t < 64; ++t){
      int h = w * 64 + t;
      float p = 0.f;
      #pragma unroll
      for (int j2 = 0; j2 < 4; ++j2)
        p += Wq[h * 256 + l + 64 * j2] * xs[l + 64 * j2];
      p = wred(p);
      if (l == 0) qs[h] = p;
    }
    __syncthreads();
    {
      int d = tid; float p = 0.f;
      for (int h = 0; h < 256; ++h) p += qs[h] * Wk[h * 256 + d];
      qks[d] = p;
    }
    __syncthreads();
    for (int t = 0; t < 16; ++t){
      int n = w * 16 + t;
      float p = 0.f;
      #pragma unroll
      for (int j2 = 0; j2 < 4; ++j2)
        p += slots[(size_t)(b * 64 + n) * 256 + l + 64 * j2] * qks[l + 64 * j2];
      p = wred(p);
      if (l == 0) sims[n] = p;
    }
    __syncthreads();
    if (tid == 0){
      int ic = 0; float best = sims[0];
      for (int n = 1; n < 64; ++n) if (sims[n] > best){ best = sims[n]; ic = n; }
      sidx = ic;
    }
  }
  __syncthreads();
  int id = sidx;
  if (tid == 0) idx_ws[b] = id;
  if (tid < 64){
    int n = tid; bool sel = (n == id);
    delta_out[b * 64 + n]  = sel ? 0.0f : (delta[b * 64 + n] + 1.0f);
    filled_out[b * 64 + n] = (sel || filled[b * 64 + n] != 0) ? 1.0f : 0.0f;
  }
}

// ---------------------------------------------------------------------------
// K2 v4b: scatter/copy + bf16 A production with non-temporal hints on the
// single-touch fp32 streams, via ext_vector f32x4 (builtin requires it).
// ---------------------------------------------------------------------------
__global__ __launch_bounds__(512) void k_scatter(
    const float* __restrict__ x, const float* __restrict__ slots,
    const float* __restrict__ cum, const int* __restrict__ idx_ws,
    const float* __restrict__ v_ws,
    float* __restrict__ slots_out, float* __restrict__ cum_out,
    unsigned short* __restrict__ abf){
  int rg = threadIdx.x >> 6, l = threadIdx.x & 63;
  int row = blockIdx.x * 8 + rg;
  int b = row >> 6, n = row & 63;
  bool sel = (n == idx_ws[b]);
  f32x4 f0, f1;
  if (l < 32){
    int k0 = l * 8;
    if (sel){
      const f32x4* src = (const f32x4*)(v_ws + (size_t)b * 256 + k0);
      f0 = src[0]; f1 = src[1];
    } else {
      const f32x4* src = (const f32x4*)(slots + (size_t)row * 256 + k0);
      f0 = __builtin_nontemporal_load(src);
      f1 = __builtin_nontemporal_load(src + 1);
    }
    f32x4* d = (f32x4*)(slots_out + (size_t)row * 256 + k0);
    __builtin_nontemporal_store(f0, d);
    __builtin_nontemporal_store(f1, d + 1);
  } else {
    int k0 = (l - 32) * 8;
    const f32x4* xp = (const f32x4*)(x + (size_t)b * 256 + k0);
    f32x4 x0 = xp[0], x1 = xp[1];
    if (sel){ f0 = x0; f1 = x1; }
    else {
      const f32x4* cp = (const f32x4*)(cum + (size_t)row * 256 + k0);
      f0 = __builtin_nontemporal_load(cp);
      f1 = __builtin_nontemporal_load(cp + 1);
      f0 += x0; f1 += x1;
    }
    f32x4* d = (f32x4*)(cum_out + (size_t)row * 256 + k0);
    __builtin_nontemporal_store(f0, d);
    __builtin_nontemporal_store(f1, d + 1);
  }
  uint4 q;
  q.x = pack2(f0[0], f0[1]); q.y = pack2(f0[2], f0[3]);
  q.z = pack2(f1[0], f1[1]); q.w = pack2(f1[2], f1[3]);
  *(uint4*)(abf + (size_t)row * 512 + l * 8) = q;   // cached: re-read by gemm
}

// ---------------------------------------------------------------------------
// K3 v15 (R18): pure bf16 GEMM, 128x256 tile, 8 waves, T4 counted-vmcnt
// depth-2 single-barrier pipeline (converged structure).
// z0 step-major: z0[(n*2048 + b)*1024 + gc] (bf16).
// ---------------------------------------------------------------------------
__global__ __launch_bounds__(512) void k_gemm(
    const unsigned short* __restrict__ abf,
    const float* __restrict__ dlt,
    const unsigned short* __restrict__ wfB,
    const float* __restrict__ wlast, const float* __restrict__ bias,
    unsigned short* __restrict__ z0){
  extern __shared__ unsigned char L[];           // 73728 B
  int tid = threadIdx.x, l = tid & 63, w = tid >> 6;
  int bid = blockIdx.x;
  int gw = (bid & 7) * 512 + (bid >> 3);         // XCD-chunked bijection (4096)
  int n_idx = gw & 3, m_idx = gw >> 2;           // 4 n-blocks x 1024 m-panels
  int m0 = m_idx * 128, n0 = n_idx * 256, bA = m0 >> 6;
  int wm = w & 1, wn = w >> 1;                   // 2 x 4 wave grid
  int cl = l & 15, lhi = l >> 4;

  auto stageA = [&](int kt, int abase){          // 8KB tile, 1 DMA/wave
    const unsigned short* s = abf + (size_t)(m0 + (w & 1) * 64 + l) * 512
                              + kt * 32 + (w >> 1) * 8;
    gload16(s, L + abase + (w >> 1) * 2048 + (w & 1) * 1024);
  };
  auto stageB = [&](int kt, int bbase){          // 16KB tile, 2 DMA/wave
    const unsigned short* s = wfB + ((size_t)(kt * 64 + n_idx * 16 + w * 2)) * 512 + l * 8;
    gload16(s,       L + bbase + (w * 2) * 1024);
    gload16(s + 512, L + bbase + (w * 2) * 1024 + 1024);
  };

  f32x4 acc[4][4];
  #pragma unroll
  for (int mi = 0; mi < 4; ++mi)
    #pragma unroll
    for (int ni = 0; ni < 4; ++ni){ f32x4 zr = {0.f,0.f,0.f,0.f}; acc[mi][ni] = zr; }

  // prologue: stage tiles 0 and 1 (6 outstanding DMA/wave)
  stageA(0, 0);      stageB(0, 24576);
  stageA(1, 8192);   stageB(1, 24576 + 16384);

  #pragma unroll
  for (int kt = 0; kt < 16; ++kt){
    // counted wait: tile kt's 3 DMAs (per wave) have landed; never drain to 0
    if (kt < 15) asm volatile("s_waitcnt vmcnt(3)" ::: "memory");
    else         asm volatile("s_waitcnt vmcnt(0)" ::: "memory");
    __builtin_amdgcn_s_barrier();                // all waves' tile-kt landed
    __builtin_amdgcn_sched_barrier(0);           // nothing hoists above barrier
    if (kt < 14){                                // stage AFTER barrier: buffer
      int nb = (kt + 2) % 3;                     // (kt+2)%3 idle since kt-1
      stageA(kt + 2, nb * 8192);
      stageB(kt + 2, 24576 + nb * 16384);
    }
    int ab = (kt % 3) * 8192, bb = 24576 + (kt % 3) * 16384;
    s16x8 a[4], bf[4];
    #pragma unroll
    for (int mi = 0; mi < 4; ++mi)
      a[mi] = *(const s16x8*)(L + ab + lhi * 2048 + (wm * 64 + mi * 16 + cl) * 16);
    #pragma unroll
    for (int ni = 0; ni < 4; ++ni)
      bf[ni] = *(const s16x8*)(L + bb + (wn * 4 + ni) * 1024 + l * 16);
    #pragma unroll
    for (int ni = 0; ni < 4; ++ni)
      #pragma unroll
      for (int mi = 0; mi < 4; ++mi)
        acc[mi][ni] = __builtin_amdgcn_mfma_f32_16x16x32_bf16(a[mi], bf[ni], acc[mi][ni], 0, 0, 0);
  }
  __syncthreads();                               // all compute done before L reuse

  // epilogue: acc -> L (z-stage, 128 rows x 512 B) -> coalesced z0 stores
  float dv[4][4];
  #pragma unroll
  for (int mi = 0; mi < 4; ++mi)
    #pragma unroll
    for (int reg = 0; reg < 4; ++reg)
      dv[mi][reg] = dlt[(bA + wm) * 64 + mi * 16 + lhi * 4 + reg];
  #pragma unroll
  for (int mi = 0; mi < 4; ++mi)
    #pragma unroll
    for (int reg = 0; reg < 4; ++reg){
      int row = wm * 64 + mi * 16 + lhi * 4 + reg;
      #pragma unroll
      for (int ni = 0; ni < 4; ++ni){
        int col = wn * 64 + ni * 16 + cl;        // 0..255
        int gc = n0 + col;
        float val = acc[mi][ni][reg] + dv[mi][reg] * wlast[gc] + bias[gc];
        *(unsigned short*)(L + row * 512 + ((col * 2) ^ ((row & 7) << 4))) = f2b(val);
      }
    }
  __syncthreads();
  #pragma unroll
  for (int rr = 0; rr < 8; ++rr){
    int id = rr * 512 + tid;                     // 4096 16B chunks
    int row = id >> 5, cs = id & 31;
    int bq = bA + (row >> 6), nq = row & 63;
    uint4 v = *(const uint4*)(L + row * 512 + ((cs * 16) ^ ((row & 7) << 4)));
    *(uint4*)(z0 + ((size_t)nq * 2048 + bq) * 1024 + n0 + cs * 8) = v;
  }
}

// ---------------------------------------------------------------------------
// K4 v12: K=64 int8 MFMA LSTM with distance-2 z0 register prefetch
// (unchanged from R23).
// ---------------------------------------------------------------------------
__global__ __launch_bounds__(512) void k_lstm(
    const unsigned short* __restrict__ z0,
    const signed char* __restrict__ wfrag8,
    float* __restrict__ hm){
  extern __shared__ unsigned char smem[];
  float* zhhf = (float*)smem;                 // [4 gates][8 rows][256 cols] = 32 KB
  unsigned char* hbf = smem + 32768;          // 16 x 256 int8 = 4 KB, swizzled
  int tid = threadIdx.x, l = tid & 63, w = tid >> 6;
  int cl = l & 15, lhi = l >> 4;
  int b0 = blockIdx.x * 8;
  int rr_o = tid >> 6;                        // owned row 0..7 (== wave id)
  int chb  = (tid & 63) * 4;                  // owned col base (4 consecutive)
  int hoff = rr_o * 256 + ((chb & ~15) ^ ((rr_o & 7) << 4)) + (chb & 15);
  const unsigned short* zbase = z0 + (size_t)(b0 + rr_o) * 1024 + chb;

  for (int i = tid; i < 1024; i += 512) ((unsigned int*)hbf)[i] = 0u;

  // resident weights: 32 frags x 16 B per wave (128 VGPRs)
  i32x4 wpin[32];
  #pragma unroll
  for (int f = 0; f < 32; ++f)
    wpin[f] = *(const i32x4*)(wfrag8 + ((size_t)w * 32 + f) * 1024 + l * 16);

  float cst[4];
  #pragma unroll
  for (int i = 0; i < 4; ++i) cst[i] = 0.f;
  const float s_comb = WSCALE / 127.0f;       // acc_i32 -> z_hh f32
  __syncthreads();

  // prologue: issue step-0 gate inputs
  u16x4 zgA[4], zgB[4];
  {
    const unsigned short* zr = zbase;
    zgA[0] = *(const u16x4*)(zr);
    zgA[1] = *(const u16x4*)(zr + 256);
    zgA[2] = *(const u16x4*)(zr + 512);
    zgA[3] = *(const u16x4*)(zr + 768);
  }

  #define LSTM_STEP(NVAL, ZGCUR, ZGNXT, NXT_OFF)                               \
  {                                                                            \
    int n = (NVAL);                                                            \
    if (n + (NXT_OFF) < 64){                                                   \
      const unsigned short* zr = zbase + (size_t)(n + (NXT_OFF)) * 2097152;    \
      ZGNXT[0] = *(const u16x4*)(zr);                                          \
      ZGNXT[1] = *(const u16x4*)(zr + 256);                                    \
      ZGNXT[2] = *(const u16x4*)(zr + 512);                                    \
      ZGNXT[3] = *(const u16x4*)(zr + 768);                                    \
    }                                                                          \
    i32x4 acc[8];                                                              \
    _Pragma("unroll")                                                          \
    for (int nt = 0; nt < 8; ++nt){ i32x4 zr4 = {0, 0, 0, 0}; acc[nt] = zr4; } \
    _Pragma("unroll")                                                          \
    for (int kt2 = 0; kt2 < 4; ++kt2){                                         \
      i32x4 a = *(const i32x4*)(hbf + cl * 256 +                               \
                 ((kt2 * 64 + lhi * 16) ^ ((cl & 7) << 4)));                   \
      _Pragma("unroll")                                                        \
      for (int nt = 0; nt < 8; ++nt)                                           \
        acc[nt] = __builtin_amdgcn_mfma_i32_16x16x64_i8(a, wpin[kt2 * 8 + nt], acc[nt], 0, 0, 0); \
    }                                                                          \
    if (l < 32){                                                               \
      _Pragma("unroll")                                                        \
      for (int hh = 0; hh < 2; ++hh){                                          \
        int ch = w * 32 + hh * 16 + cl;                                        \
        _Pragma("unroll")                                                      \
        for (int reg = 0; reg < 4; ++reg){                                     \
          int rr = lhi * 4 + reg;                                              \
          zhhf[0 * 2048 + rr * 256 + ch] = (float)acc[0 + hh][reg];            \
          zhhf[1 * 2048 + rr * 256 + ch] = (float)acc[2 + hh][reg];            \
          zhhf[2 * 2048 + rr * 256 + ch] = (float)acc[4 + hh][reg];            \
          zhhf[3 * 2048 + rr * 256 + ch] = (float)acc[6 + hh][reg];            \
        }                                                                      \
      }                                                                        \
    }                                                                          \
    __syncthreads();                                                           \
    f32x4 p[4];                                                                \
    _Pragma("unroll")                                                          \
    for (int g = 0; g < 4; ++g)                                                \
      p[g] = *(const f32x4*)(zhhf + g * 2048 + rr_o * 256 + chb);              \
    unsigned int hw = 0;                                                       \
    _Pragma("unroll")                                                          \
    for (int i = 0; i < 4; ++i){                                               \
      float zi  = fmaf(p[0][i], s_comb, b2f(ZGCUR[0][i]));                     \
      float zf  = fmaf(p[1][i], s_comb, b2f(ZGCUR[1][i]));                     \
      float zgv = fmaf(p[2][i], s_comb, b2f(ZGCUR[2][i]));                     \
      float zo  = fmaf(p[3][i], s_comb, b2f(ZGCUR[3][i]));                     \
      float cv = fsig(zf) * cst[i] + fsig(zi) * ftanh(zgv);                    \
      cst[i] = cv;                                                             \
      float hv = fsig(zo) * ftanh(cv);                                         \
      unsigned int q = (unsigned int)(__float2int_rn(hv * 127.0f) & 255);      \
      hw |= q << (8 * i);                                                      \
      if (n == 63) hm[(size_t)(b0 + rr_o) * 256 + chb + i] = hv;               \
    }                                                                          \
    *(unsigned int*)(hbf + hoff) = hw;                                         \
    __syncthreads();                                                           \
  }

  for (int n2 = 0; n2 < 64; n2 += 2){
    LSTM_STEP(n2,     zgA, zgB, 1)
    LSTM_STEP(n2 + 1, zgB, zgA, 1)
  }
  #undef LSTM_STEP
}

// ---------------------------------------------------------------------------
extern "C" void kernel_launch(void* const* d_in, const int* in_sizes, int n_in,
                              void* d_out, int out_size, void* d_ws, size_t ws_size,
                              hipStream_t stream){
  const float* x      = (const float*)d_in[0];
  const float* slots  = (const float*)d_in[2];
  const float* cum    = (const float*)d_in[3];
  const float* delta  = (const float*)d_in[4];
  const int*   filled = (const int*)d_in[5];
  const float* Wq  = (const float*)d_in[6];
  const float* Wk  = (const float*)d_in[7];
  const float* Wv  = (const float*)d_in[8];
  const float* bv  = (const float*)d_in[9];
  const float* wih = (const float*)d_in[10];
  const float* whh = (const float*)d_in[11];
  const float* bih = (const float*)d_in[12];
  const float* bhh = (const float*)d_in[13];

  float* out        = (float*)d_out;
  float* hm         = out;                 // (B,H)    524288
  float* slots_out  = out + 524288;        // (B,N,D)  33554432
  float* cum_out    = out + 34078720;      // (B,N,D)  33554432
  float* delta_out  = out + 67633152;      // (B,N)    131072
  float* filled_out = out + 67764224;      // (B,N)    131072

  char* ws = (char*)d_ws;
  int*            idx_ws  = (int*)ws;                                  // 8KB
  float*          v_ws    = (float*)(ws + 8192);                       // 2MB
  float*          bias    = (float*)(ws + 2105344);                    // 4KB
  float*          wlast   = (float*)(ws + 2109440);                    // 4KB
  unsigned short* wfB     = (unsigned short*)(ws + 2113536);           // 1MB
  signed char*    wfrag8  = (signed char*)(ws + 3162112);              // 256KB
  unsigned short* abf     = (unsigned short*)(ws + 3686400);           // 128MB
  unsigned short* z0      = (unsigned short*)(ws + 3686400 + 134217728); // 256MB

  k_route<<<dim3(4096), dim3(256), 0, stream>>>(x, slots, delta, filled,
                                                Wq, Wk, Wv, bv,
                                                wih, whh, bih, bhh,
                                                idx_ws, v_ws, delta_out, filled_out,
                                                wfB, wfrag8, bias, wlast);
  k_scatter<<<dim3(16384), dim3(512), 0, stream>>>(x, slots, cum, idx_ws, v_ws,
                                                   slots_out, cum_out, abf);
  k_gemm<<<dim3(4096), dim3(512), 73728, stream>>>(abf, delta_out,
                                                   wfB, wlast, bias, z0);
  k_lstm<<<dim3(256), dim3(512), 36864, stream>>>(z0, wfrag8, hm);
}

// Round 26
// 516.838 us; speedup vs baseline: 1.0105x; 1.0105x over previous
//
#include <hip/hip_runtime.h>
#include <hip/hip_bf16.h>
#include <cstdint>
#include <cstddef>

// B=2048, D=256, H=256, N=64, F=513, 4H=1024

typedef short s16x8 __attribute__((ext_vector_type(8)));
typedef float f32x4 __attribute__((ext_vector_type(4)));
typedef int   i32x4 __attribute__((ext_vector_type(4)));
typedef unsigned short u16x4 __attribute__((ext_vector_type(4)));

static __device__ __forceinline__ unsigned short f2b(float f){
  union{float f; unsigned int u;} v; v.f = f;
  unsigned int r = v.u + 0x7fffu + ((v.u >> 16) & 1u);   // RNE
  return (unsigned short)(r >> 16);
}
static __device__ __forceinline__ float b2f(unsigned short h){
  union{unsigned int u; float f;} v; v.u = ((unsigned int)h) << 16; return v.f;
}
static __device__ __forceinline__ unsigned int pack2(float a, float b){
  return (unsigned int)f2b(a) | ((unsigned int)f2b(b) << 16);
}
static __device__ __forceinline__ float fsig(float x){ return 1.0f / (1.0f + __expf(-x)); }
static __device__ __forceinline__ float ftanh(float x){ return 2.0f / (1.0f + __expf(-2.0f * x)) - 1.0f; }
static __device__ __forceinline__ float wred(float p){
  p += __shfl_down(p, 32); p += __shfl_down(p, 16); p += __shfl_down(p, 8);
  p += __shfl_down(p, 4);  p += __shfl_down(p, 2);  p += __shfl_down(p, 1);
  return p;
}
// async global->LDS, 16 B per lane; lds base wave-uniform, global src per-lane
static __device__ __forceinline__ void gload16(const void* g, void* lds){
  __builtin_amdgcn_global_load_lds(
      (const __attribute__((address_space(1))) unsigned int*)g,
      (__attribute__((address_space(3))) unsigned int*)lds, 16, 0, 0);
}

#define WSCALE (0.30f / 127.0f)      // W_hh i8 scale

// ---------------------------------------------------------------------------
// K1+K0 fused: blocks 0..2047 = routing; blocks 2048..4095 = weight prep.
// ---------------------------------------------------------------------------
__global__ __launch_bounds__(256) void k_route(
    const float* __restrict__ x, const float* __restrict__ slots,
    const float* __restrict__ delta, const int* __restrict__ filled,
    const float* __restrict__ Wq, const float* __restrict__ Wk,
    const float* __restrict__ Wv, const float* __restrict__ bv,
    const float* __restrict__ wih, const float* __restrict__ whh,
    const float* __restrict__ bih, const float* __restrict__ bhh,
    int* __restrict__ idx_ws, float* __restrict__ v_ws,
    float* __restrict__ delta_out, float* __restrict__ filled_out,
    unsigned short* __restrict__ wfB, signed char* __restrict__ wfrag8,
    float* __restrict__ bias, float* __restrict__ wlast){
  int tid = threadIdx.x;
  if (blockIdx.x >= 2048){                 // ---- prep branch ----
    int id = (blockIdx.x - 2048) * 256 + tid;   // covers 524288
    { // wfB: 1024 frags * 512 entries, kt-major
      int frag = id >> 9;
      int l = (id >> 3) & 63;
      int j = id & 7;
      int kt = frag >> 6, ct = frag & 63;
      int col = ct * 16 + (l & 15);
      int k   = kt * 32 + (l >> 4) * 8 + j;
      wfB[id] = f2b(wih[col * 513 + k]);
    }
    if (id < 262144){ // wfrag8: 256 frags * 64 lanes * 16 B (K=64 layout)
      int frag = id >> 10;
      int lane = (id >> 4) & 63;
      int j    = id & 15;
      int w   = frag >> 5;
      int kt2 = (frag >> 3) & 3;
      int nt  = frag & 7;
      int g   = nt >> 1, hh = nt & 1;
      int colg = g * 256 + w * 32 + hh * 16 + (lane & 15);
      int k    = kt2 * 64 + (lane >> 4) * 16 + j;
      int q = __float2int_rn(whh[colg * 256 + k] * (1.0f / WSCALE));
      q = q > 127 ? 127 : (q < -127 ? -127 : q);
      wfrag8[id] = (signed char)q;
    }
    if (id < 1024){
      bias[id]  = bih[id] + bhh[id];
      wlast[id] = wih[id * 513 + 512];
    }
    return;
  }
  // ---- routing branch ----
  int b = blockIdx.x, l = tid & 63, w = tid >> 6;
  __shared__ float xs[256], qs[256], qks[256], sims[64];
  __shared__ int sidx;
  xs[tid] = x[b * 256 + tid];
  if (tid < 64){
    unsigned long long em = __ballot(filled[b * 64 + tid] == 0);
    if (tid == 0) sidx = em ? (int)__builtin_ctzll(em) : -1;
  }
  __syncthreads();
  for (int t = 0; t < 64; ++t){
    int h = w * 64 + t;
    float pv = 0.f;
    #pragma unroll
    for (int j2 = 0; j2 < 4; ++j2)
      pv += Wv[h * 256 + l + 64 * j2] * xs[l + 64 * j2];
    pv = wred(pv);
    if (l == 0) v_ws[b * 256 + h] = pv + bv[h];
  }
  if (sidx < 0){           // rare fallback: content-based argmax
    for (int t = 0; t < 64; ++t){
      int h = w * 64 + t;
      float p = 0.f;
      #pragma unroll
      for (int j2 = 0; j2 < 4; ++j2)
        p += Wq[h * 256 + l + 64 * j2] * xs[l + 64 * j2];
      p = wred(p);
      if (l == 0) qs[h] = p;
    }
    __syncthreads();
    {
      int d = tid; float p = 0.f;
      for (int h = 0; h < 256; ++h) p += qs[h] * Wk[h * 256 + d];
      qks[d] = p;
    }
    __syncthreads();
    for (int t = 0; t < 16; ++t){
      int n = w * 16 + t;
      float p = 0.f;
      #pragma unroll
      for (int j2 = 0; j2 < 4; ++j2)
        p += slots[(size_t)(b * 64 + n) * 256 + l + 64 * j2] * qks[l + 64 * j2];
      p = wred(p);
      if (l == 0) sims[n] = p;
    }
    __syncthreads();
    if (tid == 0){
      int ic = 0; float best = sims[0];
      for (int n = 1; n < 64; ++n) if (sims[n] > best){ best = sims[n]; ic = n; }
      sidx = ic;
    }
  }
  __syncthreads();
  int id = sidx;
  if (tid == 0) idx_ws[b] = id;
  if (tid < 64){
    int n = tid; bool sel = (n == id);
    delta_out[b * 64 + n]  = sel ? 0.0f : (delta[b * 64 + n] + 1.0f);
    filled_out[b * 64 + n] = (sel || filled[b * 64 + n] != 0) ? 1.0f : 0.0f;
  }
}

// ---------------------------------------------------------------------------
// K2 v3 (R23, NT hints reverted): scatter/copy + bf16 A production.
// 512-thread blocks, 8 rows each, grid 16384.
// ---------------------------------------------------------------------------
__global__ __launch_bounds__(512) void k_scatter(
    const float* __restrict__ x, const float* __restrict__ slots,
    const float* __restrict__ cum, const int* __restrict__ idx_ws,
    const float* __restrict__ v_ws,
    float* __restrict__ slots_out, float* __restrict__ cum_out,
    unsigned short* __restrict__ abf){
  int rg = threadIdx.x >> 6, l = threadIdx.x & 63;
  int row = blockIdx.x * 8 + rg;
  int b = row >> 6, n = row & 63;
  bool sel = (n == idx_ws[b]);
  float4 f0, f1;
  if (l < 32){
    int k0 = l * 8;
    const float* src = sel ? (v_ws + (size_t)b * 256 + k0)
                           : (slots + (size_t)row * 256 + k0);
    f0 = ((const float4*)src)[0]; f1 = ((const float4*)src)[1];
    float4* d = (float4*)(slots_out + (size_t)row * 256 + k0);
    d[0] = f0; d[1] = f1;
  } else {
    int k0 = (l - 32) * 8;
    const float4* xp = (const float4*)(x + (size_t)b * 256 + k0);
    float4 x0 = xp[0], x1 = xp[1];
    if (sel){ f0 = x0; f1 = x1; }
    else {
      const float4* cp = (const float4*)(cum + (size_t)row * 256 + k0);
      f0 = cp[0]; f1 = cp[1];
      f0.x += x0.x; f0.y += x0.y; f0.z += x0.z; f0.w += x0.w;
      f1.x += x1.x; f1.y += x1.y; f1.z += x1.z; f1.w += x1.w;
    }
    float4* d = (float4*)(cum_out + (size_t)row * 256 + k0);
    d[0] = f0; d[1] = f1;
  }
  uint4 q;
  q.x = pack2(f0.x, f0.y); q.y = pack2(f0.z, f0.w);
  q.z = pack2(f1.x, f1.y); q.w = pack2(f1.z, f1.w);
  *(uint4*)(abf + (size_t)row * 512 + l * 8) = q;   // l*8 covers both halves
}

// ---------------------------------------------------------------------------
// K3 v15 (R18): pure bf16 GEMM, 128x256 tile, 8 waves, T4 counted-vmcnt
// depth-2 single-barrier pipeline (converged structure).
// z0 step-major: z0[(n*2048 + b)*1024 + gc] (bf16).
// ---------------------------------------------------------------------------
__global__ __launch_bounds__(512) void k_gemm(
    const unsigned short* __restrict__ abf,
    const float* __restrict__ dlt,
    const unsigned short* __restrict__ wfB,
    const float* __restrict__ wlast, const float* __restrict__ bias,
    unsigned short* __restrict__ z0){
  extern __shared__ unsigned char L[];           // 73728 B
  int tid = threadIdx.x, l = tid & 63, w = tid >> 6;
  int bid = blockIdx.x;
  int gw = (bid & 7) * 512 + (bid >> 3);         // XCD-chunked bijection (4096)
  int n_idx = gw & 3, m_idx = gw >> 2;           // 4 n-blocks x 1024 m-panels
  int m0 = m_idx * 128, n0 = n_idx * 256, bA = m0 >> 6;
  int wm = w & 1, wn = w >> 1;                   // 2 x 4 wave grid
  int cl = l & 15, lhi = l >> 4;

  auto stageA = [&](int kt, int abase){          // 8KB tile, 1 DMA/wave
    const unsigned short* s = abf + (size_t)(m0 + (w & 1) * 64 + l) * 512
                              + kt * 32 + (w >> 1) * 8;
    gload16(s, L + abase + (w >> 1) * 2048 + (w & 1) * 1024);
  };
  auto stageB = [&](int kt, int bbase){          // 16KB tile, 2 DMA/wave
    const unsigned short* s = wfB + ((size_t)(kt * 64 + n_idx * 16 + w * 2)) * 512 + l * 8;
    gload16(s,       L + bbase + (w * 2) * 1024);
    gload16(s + 512, L + bbase + (w * 2) * 1024 + 1024);
  };

  f32x4 acc[4][4];
  #pragma unroll
  for (int mi = 0; mi < 4; ++mi)
    #pragma unroll
    for (int ni = 0; ni < 4; ++ni){ f32x4 zr = {0.f,0.f,0.f,0.f}; acc[mi][ni] = zr; }

  // prologue: stage tiles 0 and 1 (6 outstanding DMA/wave)
  stageA(0, 0);      stageB(0, 24576);
  stageA(1, 8192);   stageB(1, 24576 + 16384);

  #pragma unroll
  for (int kt = 0; kt < 16; ++kt){
    // counted wait: tile kt's 3 DMAs (per wave) have landed; never drain to 0
    if (kt < 15) asm volatile("s_waitcnt vmcnt(3)" ::: "memory");
    else         asm volatile("s_waitcnt vmcnt(0)" ::: "memory");
    __builtin_amdgcn_s_barrier();                // all waves' tile-kt landed
    __builtin_amdgcn_sched_barrier(0);           // nothing hoists above barrier
    if (kt < 14){                                // stage AFTER barrier: buffer
      int nb = (kt + 2) % 3;                     // (kt+2)%3 idle since kt-1
      stageA(kt + 2, nb * 8192);
      stageB(kt + 2, 24576 + nb * 16384);
    }
    int ab = (kt % 3) * 8192, bb = 24576 + (kt % 3) * 16384;
    s16x8 a[4], bf[4];
    #pragma unroll
    for (int mi = 0; mi < 4; ++mi)
      a[mi] = *(const s16x8*)(L + ab + lhi * 2048 + (wm * 64 + mi * 16 + cl) * 16);
    #pragma unroll
    for (int ni = 0; ni < 4; ++ni)
      bf[ni] = *(const s16x8*)(L + bb + (wn * 4 + ni) * 1024 + l * 16);
    #pragma unroll
    for (int ni = 0; ni < 4; ++ni)
      #pragma unroll
      for (int mi = 0; mi < 4; ++mi)
        acc[mi][ni] = __builtin_amdgcn_mfma_f32_16x16x32_bf16(a[mi], bf[ni], acc[mi][ni], 0, 0, 0);
  }
  __syncthreads();                               // all compute done before L reuse

  // epilogue: acc -> L (z-stage, 128 rows x 512 B) -> coalesced z0 stores
  float dv[4][4];
  #pragma unroll
  for (int mi = 0; mi < 4; ++mi)
    #pragma unroll
    for (int reg = 0; reg < 4; ++reg)
      dv[mi][reg] = dlt[(bA + wm) * 64 + mi * 16 + lhi * 4 + reg];
  #pragma unroll
  for (int mi = 0; mi < 4; ++mi)
    #pragma unroll
    for (int reg = 0; reg < 4; ++reg){
      int row = wm * 64 + mi * 16 + lhi * 4 + reg;
      #pragma unroll
      for (int ni = 0; ni < 4; ++ni){
        int col = wn * 64 + ni * 16 + cl;        // 0..255
        int gc = n0 + col;
        float val = acc[mi][ni][reg] + dv[mi][reg] * wlast[gc] + bias[gc];
        *(unsigned short*)(L + row * 512 + ((col * 2) ^ ((row & 7) << 4))) = f2b(val);
      }
    }
  __syncthreads();
  #pragma unroll
  for (int rr = 0; rr < 8; ++rr){
    int id = rr * 512 + tid;                     // 4096 16B chunks
    int row = id >> 5, cs = id & 31;
    int bq = bA + (row >> 6), nq = row & 63;
    uint4 v = *(const uint4*)(L + row * 512 + ((cs * 16) ^ ((row & 7) << 4)));
    *(uint4*)(z0 + ((size_t)nq * 2048 + bq) * 1024 + n0 + cs * 8) = v;
  }
}

// ---------------------------------------------------------------------------
// K4 v12: K=64 int8 MFMA LSTM with distance-2 z0 register prefetch.
// ---------------------------------------------------------------------------
__global__ __launch_bounds__(512) void k_lstm(
    const unsigned short* __restrict__ z0,
    const signed char* __restrict__ wfrag8,
    float* __restrict__ hm){
  extern __shared__ unsigned char smem[];
  float* zhhf = (float*)smem;                 // [4 gates][8 rows][256 cols] = 32 KB
  unsigned char* hbf = smem + 32768;          // 16 x 256 int8 = 4 KB, swizzled
  int tid = threadIdx.x, l = tid & 63, w = tid >> 6;
  int cl = l & 15, lhi = l >> 4;
  int b0 = blockIdx.x * 8;
  int rr_o = tid >> 6;                        // owned row 0..7 (== wave id)
  int chb  = (tid & 63) * 4;                  // owned col base (4 consecutive)
  int hoff = rr_o * 256 + ((chb & ~15) ^ ((rr_o & 7) << 4)) + (chb & 15);
  const unsigned short* zbase = z0 + (size_t)(b0 + rr_o) * 1024 + chb;

  for (int i = tid; i < 1024; i += 512) ((unsigned int*)hbf)[i] = 0u;

  // resident weights: 32 frags x 16 B per wave (128 VGPRs)
  i32x4 wpin[32];
  #pragma unroll
  for (int f = 0; f < 32; ++f)
    wpin[f] = *(const i32x4*)(wfrag8 + ((size_t)w * 32 + f) * 1024 + l * 16);

  float cst[4];
  #pragma unroll
  for (int i = 0; i < 4; ++i) cst[i] = 0.f;
  const float s_comb = WSCALE / 127.0f;       // acc_i32 -> z_hh f32
  __syncthreads();

  // prologue: issue step-0 gate inputs
  u16x4 zgA[4], zgB[4];
  {
    const unsigned short* zr = zbase;
    zgA[0] = *(const u16x4*)(zr);
    zgA[1] = *(const u16x4*)(zr + 256);
    zgA[2] = *(const u16x4*)(zr + 512);
    zgA[3] = *(const u16x4*)(zr + 768);
  }

  #define LSTM_STEP(NVAL, ZGCUR, ZGNXT, NXT_OFF)                               \
  {                                                                            \
    int n = (NVAL);                                                            \
    if (n + (NXT_OFF) < 64){                                                   \
      const unsigned short* zr = zbase + (size_t)(n + (NXT_OFF)) * 2097152;    \
      ZGNXT[0] = *(const u16x4*)(zr);                                          \
      ZGNXT[1] = *(const u16x4*)(zr + 256);                                    \
      ZGNXT[2] = *(const u16x4*)(zr + 512);                                    \
      ZGNXT[3] = *(const u16x4*)(zr + 768);                                    \
    }                                                                          \
    i32x4 acc[8];                                                              \
    _Pragma("unroll")                                                          \
    for (int nt = 0; nt < 8; ++nt){ i32x4 zr4 = {0, 0, 0, 0}; acc[nt] = zr4; } \
    _Pragma("unroll")                                                          \
    for (int kt2 = 0; kt2 < 4; ++kt2){                                         \
      i32x4 a = *(const i32x4*)(hbf + cl * 256 +                               \
                 ((kt2 * 64 + lhi * 16) ^ ((cl & 7) << 4)));                   \
      _Pragma("unroll")                                                        \
      for (int nt = 0; nt < 8; ++nt)                                           \
        acc[nt] = __builtin_amdgcn_mfma_i32_16x16x64_i8(a, wpin[kt2 * 8 + nt], acc[nt], 0, 0, 0); \
    }                                                                          \
    if (l < 32){                                                               \
      _Pragma("unroll")                                                        \
      for (int hh = 0; hh < 2; ++hh){                                          \
        int ch = w * 32 + hh * 16 + cl;                                        \
        _Pragma("unroll")                                                      \
        for (int reg = 0; reg < 4; ++reg){                                     \
          int rr = lhi * 4 + reg;                                              \
          zhhf[0 * 2048 + rr * 256 + ch] = (float)acc[0 + hh][reg];            \
          zhhf[1 * 2048 + rr * 256 + ch] = (float)acc[2 + hh][reg];            \
          zhhf[2 * 2048 + rr * 256 + ch] = (float)acc[4 + hh][reg];            \
          zhhf[3 * 2048 + rr * 256 + ch] = (float)acc[6 + hh][reg];            \
        }                                                                      \
      }                                                                        \
    }                                                                          \
    __syncthreads();                                                           \
    f32x4 p[4];                                                                \
    _Pragma("unroll")                                                          \
    for (int g = 0; g < 4; ++g)                                                \
      p[g] = *(const f32x4*)(zhhf + g * 2048 + rr_o * 256 + chb);              \
    unsigned int hw = 0;                                                       \
    _Pragma("unroll")                                                          \
    for (int i = 0; i < 4; ++i){                                               \
      float zi  = fmaf(p[0][i], s_comb, b2f(ZGCUR[0][i]));                     \
      float zf  = fmaf(p[1][i], s_comb, b2f(ZGCUR[1][i]));                     \
      float zgv = fmaf(p[2][i], s_comb, b2f(ZGCUR[2][i]));                     \
      float zo  = fmaf(p[3][i], s_comb, b2f(ZGCUR[3][i]));                     \
      float cv = fsig(zf) * cst[i] + fsig(zi) * ftanh(zgv);                    \
      cst[i] = cv;                                                             \
      float hv = fsig(zo) * ftanh(cv);                                         \
      unsigned int q = (unsigned int)(__float2int_rn(hv * 127.0f) & 255);      \
      hw |= q << (8 * i);                                                      \
      if (n == 63) hm[(size_t)(b0 + rr_o) * 256 + chb + i] = hv;               \
    }                                                                          \
    *(unsigned int*)(hbf + hoff) = hw;                                         \
    __syncthreads();                                                           \
  }

  for (int n2 = 0; n2 < 64; n2 += 2){
    LSTM_STEP(n2,     zgA, zgB, 1)
    LSTM_STEP(n2 + 1, zgB, zgA, 1)
  }
  #undef LSTM_STEP
}

// ---------------------------------------------------------------------------
extern "C" void kernel_launch(void* const* d_in, const int* in_sizes, int n_in,
                              void* d_out, int out_size, void* d_ws, size_t ws_size,
                              hipStream_t stream){
  const float* x      = (const float*)d_in[0];
  const float* slots  = (const float*)d_in[2];
  const float* cum    = (const float*)d_in[3];
  const float* delta  = (const float*)d_in[4];
  const int*   filled = (const int*)d_in[5];
  const float* Wq  = (const float*)d_in[6];
  const float* Wk  = (const float*)d_in[7];
  const float* Wv  = (const float*)d_in[8];
  const float* bv  = (const float*)d_in[9];
  const float* wih = (const float*)d_in[10];
  const float* whh = (const float*)d_in[11];
  const float* bih = (const float*)d_in[12];
  const float* bhh = (const float*)d_in[13];

  float* out        = (float*)d_out;
  float* hm         = out;                 // (B,H)    524288
  float* slots_out  = out + 524288;        // (B,N,D)  33554432
  float* cum_out    = out + 34078720;      // (B,N,D)  33554432
  float* delta_out  = out + 67633152;      // (B,N)    131072
  float* filled_out = out + 67764224;      // (B,N)    131072

  char* ws = (char*)d_ws;
  int*            idx_ws  = (int*)ws;                                  // 8KB
  float*          v_ws    = (float*)(ws + 8192);                       // 2MB
  float*          bias    = (float*)(ws + 2105344);                    // 4KB
  float*          wlast   = (float*)(ws + 2109440);                    // 4KB
  unsigned short* wfB     = (unsigned short*)(ws + 2113536);           // 1MB
  signed char*    wfrag8  = (signed char*)(ws + 3162112);              // 256KB
  unsigned short* abf     = (unsigned short*)(ws + 3686400);           // 128MB
  unsigned short* z0      = (unsigned short*)(ws + 3686400 + 134217728); // 256MB

  k_route<<<dim3(4096), dim3(256), 0, stream>>>(x, slots, delta, filled,
                                                Wq, Wk, Wv, bv,
                                                wih, whh, bih, bhh,
                                                idx_ws, v_ws, delta_out, filled_out,
                                                wfB, wfrag8, bias, wlast);
  k_scatter<<<dim3(16384), dim3(512), 0, stream>>>(x, slots, cum, idx_ws, v_ws,
                                                   slots_out, cum_out, abf);
  k_gemm<<<dim3(4096), dim3(512), 73728, stream>>>(abf, delta_out,
                                                   wfB, wlast, bias, z0);
  k_lstm<<<dim3(256), dim3(512), 36864, stream>>>(z0, wfrag8, hm);
}